// Round 2
// baseline (385.896 us; speedup 1.0000x reference)
//
#include <hip/hip_runtime.h>
#include <math.h>

#define BB     1024
#define CC     256
#define HWN    361
#define SEH    64
#define P3C    768
#define SLICE  (CC * HWN)     // 92416 floats per batch row
#define SLICE4 (SLICE / 4)    // 23104 float4s (92416*4 bytes % 16 == 0)

// One block per batch row b. Phases: stage mask -> pool (wave/row) ->
// tiny MLP in-LDS -> apply (float4 flat, gamma/beta/mask from LDS).
// Second read of x[b] (370 KB) is expected to hit L2/L3.
__global__ __launch_bounds__(256, 4) void k_se_fused(
        const float* __restrict__ x,
        const float* __restrict__ mask,
        const float* __restrict__ msum,
        const float* __restrict__ msqrt,
        const float* __restrict__ w1,
        const float* __restrict__ b1,
        const float* __restrict__ w2,
        const float* __restrict__ b2,
        float* __restrict__ out) {
    __shared__ float m_s[HWN];        // mask row
    __shared__ float p_s[P3C];        // pooled vector [mean | mean*bs | max]
    __shared__ float part_s[4 * SEH]; // layer-1 partial dots
    __shared__ float hid_s[SEH];
    __shared__ float g_s[CC];         // sigmoid(gamma)
    __shared__ float be_s[CC];        // beta

    const int tid  = threadIdx.x;
    const int lane = tid & 63;
    const int wv   = tid >> 6;
    const int b    = blockIdx.x;

    const float* xb = x + (size_t)b * SLICE;

    // ---- stage mask row (1.4 KB) ----
    const float* mr = mask + (size_t)b * HWN;
    for (int i = tid; i < HWN; i += 256) m_s[i] = mr[i];
    __syncthreads();

    const float inv_div = 1.0f / msum[b];
    const float bscale  = (msqrt[b] - 14.0f) * 0.1f;   // (sqrt(div)-B_AVG)/10

    // ---- phase 1: pool. wave wv owns rows c = wv*64 .. wv*64+63 ----
    for (int k = 0; k < 64; ++k) {
        const int c = wv * 64 + k;
        const float* xr = xb + c * HWN;
        float s  = 0.0f;
        float mx = -INFINITY;
        for (int i = lane; i < HWN; i += 64) {
            float v = xr[i];
            s += v;                                        // raw (unmasked) sum
            mx = fmaxf(mx, fmaf(1.0f - m_s[i], -5000.0f, v));
        }
        #pragma unroll
        for (int off = 32; off; off >>= 1) {
            s  += __shfl_xor(s, off);
            mx  = fmaxf(mx, __shfl_xor(mx, off));
        }
        if (lane == 0) {
            float mean = s * inv_div;
            p_s[c]        = mean;
            p_s[256 + c]  = mean * bscale;
            p_s[512 + c]  = mx;
        }
    }
    __syncthreads();

    // ---- phase 2a: layer 1 (768 -> 64), 4 partial dots per output ----
    {
        const int q = tid >> 6, s = tid & 63;
        const float* w1r = w1  + s * P3C + q * 192;
        const float* pp  = p_s + q * 192;
        float acc = 0.0f;
        #pragma unroll 8
        for (int j = 0; j < 192; ++j) acc = fmaf(pp[j], w1r[j], acc);
        part_s[q * SEH + s] = acc;
    }
    __syncthreads();
    if (tid < SEH) {
        float h = b1[tid] + part_s[tid] + part_s[SEH + tid]
                + part_s[2 * SEH + tid] + part_s[3 * SEH + tid];
        hid_s[tid] = fmaxf(h, 0.0f);
    }
    __syncthreads();

    // ---- phase 2b: layer 2 (64 -> 512); thread t -> gamma[t], beta[t] ----
    {
        float a0 = b2[tid];
        float a1 = b2[tid + 256];
        const float* w2r0 = w2 + (size_t)tid * SEH;
        const float* w2r1 = w2 + (size_t)(tid + 256) * SEH;
        #pragma unroll 8
        for (int ss = 0; ss < SEH; ++ss) {
            float h = hid_s[ss];
            a0 = fmaf(h, w2r0[ss], a0);
            a1 = fmaf(h, w2r1[ss], a1);
        }
        g_s[tid]  = 1.0f / (1.0f + __expf(-a0));
        be_s[tid] = a1;
    }
    __syncthreads();

    // ---- phase 3: apply, float4 over the flat slice ----
    const float4* x4 = (const float4*)xb;
    float4*       o4 = (float4*)(out + (size_t)b * SLICE);
    for (int i = tid; i < SLICE4; i += 256) {
        float4 v = x4[i];
        const unsigned e0 = (unsigned)i * 4u;
        float* vp = (float*)&v;
        #pragma unroll
        for (int j = 0; j < 4; ++j) {
            unsigned e  = e0 + j;
            unsigned c  = e / 361u;            // compiler magic-mul
            unsigned hw = e - c * 361u;
            vp[j] = fmaf(g_s[c], vp[j], be_s[c]) * m_s[hw];
        }
        o4[i] = v;
    }
}

extern "C" void kernel_launch(void* const* d_in, const int* in_sizes, int n_in,
                              void* d_out, int out_size, void* d_ws, size_t ws_size,
                              hipStream_t stream) {
    const float* x     = (const float*)d_in[0];
    const float* mask  = (const float*)d_in[1];
    const float* msum  = (const float*)d_in[2];
    const float* msqrt = (const float*)d_in[3];
    const float* w1    = (const float*)d_in[4];
    const float* b1    = (const float*)d_in[5];
    const float* w2    = (const float*)d_in[6];
    const float* b2    = (const float*)d_in[7];
    float* out = (float*)d_out;

    k_se_fused<<<BB, 256, 0, stream>>>(x, mask, msum, msqrt, w1, b1, w2, b2, out);
}

// Round 4
// 233.550 us; speedup vs baseline: 1.6523x; 1.6523x over previous
//
#include <hip/hip_runtime.h>
#include <math.h>

#define BB     1024
#define CC     256
#define HWN    361
#define SEH    64
#define P3C    768
#define SLICE  (CC * HWN)     // 92416 floats per batch row
#define SLICE4 (SLICE / 4)    // 23104 float4s
#define NW     16             // waves per block

typedef float f32x4 __attribute__((ext_vector_type(4)));

// One block (1024 threads, 16 waves) per batch row b.
// Phases: stage mask -> pool (16 rows/wave) -> tiny MLP in-LDS -> apply.
__global__ __launch_bounds__(1024, 2) void k_se_fused(
        const float* __restrict__ x,
        const float* __restrict__ mask,
        const float* __restrict__ msum,
        const float* __restrict__ msqrt,
        const float* __restrict__ w1,
        const float* __restrict__ b1,
        const float* __restrict__ w2,
        const float* __restrict__ b2,
        float* __restrict__ out) {
    __shared__ float m_s[HWN];          // mask row
    __shared__ float p_s[P3C];          // pooled vector [mean | mean*bs | max]
    __shared__ float part_s[NW * SEH];  // layer-1 partial dots
    __shared__ float hid_s[SEH];
    __shared__ float g_s[CC];           // sigmoid(gamma)
    __shared__ float be_s[CC];          // beta

    const int tid  = threadIdx.x;
    const int lane = tid & 63;
    const int wv   = tid >> 6;          // 0..15
    const int b    = blockIdx.x;

    const float* xb = x + (size_t)b * SLICE;

    // ---- stage mask row ----
    if (tid < HWN) m_s[tid] = mask[(size_t)b * HWN + tid];
    __syncthreads();

    const float inv_div = 1.0f / msum[b];
    const float bscale  = (msqrt[b] - 14.0f) * 0.1f;   // (sqrt(div)-B_AVG)/10

    // ---- phase 1: pool. wave wv owns rows c = wv*16 .. wv*16+15 ----
    #pragma unroll 2
    for (int k = 0; k < 16; ++k) {
        const int c = wv * 16 + k;
        const float* xr = xb + c * HWN;
        float s  = 0.0f;
        float mx = -INFINITY;
        #pragma unroll
        for (int i = lane; i < HWN; i += 64) {
            float v = xr[i];
            s += v;                                        // raw (unmasked) sum
            mx = fmaxf(mx, fmaf(1.0f - m_s[i], -5000.0f, v));
        }
        #pragma unroll
        for (int off = 32; off; off >>= 1) {
            s  += __shfl_xor(s, off);
            mx  = fmaxf(mx, __shfl_xor(mx, off));
        }
        if (lane == 0) {
            float mean = s * inv_div;
            p_s[c]        = mean;
            p_s[256 + c]  = mean * bscale;
            p_s[512 + c]  = mx;
        }
    }
    __syncthreads();

    // ---- phase 2a: layer 1 (768 -> 64), 16 partial dots (48 long) per output --
    {
        const int q = tid >> 6, s = tid & 63;
        const float* w1r = w1  + s * P3C + q * 48;
        const float* pp  = p_s + q * 48;
        float acc = 0.0f;
        #pragma unroll 8
        for (int j = 0; j < 48; ++j) acc = fmaf(pp[j], w1r[j], acc);
        part_s[q * SEH + s] = acc;
    }
    __syncthreads();
    if (tid < SEH) {
        float h = b1[tid];
        #pragma unroll
        for (int q = 0; q < NW; ++q) h += part_s[q * SEH + tid];
        hid_s[tid] = fmaxf(h, 0.0f);
    }
    __syncthreads();

    // ---- phase 2b: layer 2 (64 -> 512); threads 0..511 ----
    if (tid < 512) {
        float a = b2[tid];
        const float* w2r = w2 + (size_t)tid * SEH;
        #pragma unroll 8
        for (int ss = 0; ss < SEH; ++ss) a = fmaf(hid_s[ss], w2r[ss], a);
        if (tid < 256) g_s[tid]        = 1.0f / (1.0f + __expf(-a));
        else           be_s[tid - 256] = a;
    }
    __syncthreads();

    // ---- phase 3: apply, float4 over the flat slice; NT stores ----
    const f32x4* x4 = (const f32x4*)xb;
    f32x4*       o4 = (f32x4*)(out + (size_t)b * SLICE);
    for (int i = tid; i < SLICE4; i += 1024) {
        f32x4 v = x4[i];
        const unsigned e0 = (unsigned)i * 4u;
        #pragma unroll
        for (int j = 0; j < 4; ++j) {
            unsigned e  = e0 + j;
            unsigned c  = e / 361u;            // compiler magic-mul
            unsigned hw = e - c * 361u;
            v[j] = fmaf(g_s[c], v[j], be_s[c]) * m_s[hw];
        }
        __builtin_nontemporal_store(v, &o4[i]);
    }
}

extern "C" void kernel_launch(void* const* d_in, const int* in_sizes, int n_in,
                              void* d_out, int out_size, void* d_ws, size_t ws_size,
                              hipStream_t stream) {
    const float* x     = (const float*)d_in[0];
    const float* mask  = (const float*)d_in[1];
    const float* msum  = (const float*)d_in[2];
    const float* msqrt = (const float*)d_in[3];
    const float* w1    = (const float*)d_in[4];
    const float* b1    = (const float*)d_in[5];
    const float* w2    = (const float*)d_in[6];
    const float* b2    = (const float*)d_in[7];
    float* out = (float*)d_out;

    k_se_fused<<<BB, 1024, 0, stream>>>(x, mask, msum, msqrt, w1, b1, w2, b2, out);
}